// Round 1
// baseline (651.943 us; speedup 1.0000x reference)
//
#include <hip/hip_runtime.h>
#include <hip/hip_bf16.h>
#include <math.h>

// ---------------------------------------------------------------------------
// DynamicGCN: 3x (GCNConv -> ReLU -> *gate)
//   gcn_conv: h = x@W ; out = scatter_add(h[src]*norm, dst) + h/deg + b
//   norm = rsqrt(deg[src])*rsqrt(deg[dst]), deg = indeg+1 (self loop)
// Strategy:
//   - gate (128 floats) computed once (tiny MLP on timestamp)
//   - deg/dinv/CSR bucketing of edges by dst computed ONCE (same for all 3
//     layers) -> aggregation with no float atomics
//   - per layer: tiled fp32 GEMM (no fp32 MFMA on CDNA4) then per-node wave
//     aggregation (64 lanes x float2 = 128 features)
// ---------------------------------------------------------------------------

#define D 128   // feature dim (D_IN == HID == 128)

// ---------------- gate: sigmoid(tanh(t*Wg1+bg1)@Wg2+bg2) -------------------
__global__ __launch_bounds__(128) void gate_kernel(
    const float* __restrict__ t, const float* __restrict__ Wg1,
    const float* __restrict__ bg1, const float* __restrict__ Wg2,
    const float* __restrict__ bg2, float* __restrict__ gate)
{
    __shared__ float u[D];
    int j = threadIdx.x;
    float tv = t[0];
    u[j] = tanhf(tv * Wg1[j] + bg1[j]);
    __syncthreads();
    float s = bg2[j];
    #pragma unroll 8
    for (int k = 0; k < D; k++) s += u[k] * Wg2[k * D + j];
    gate[j] = 1.0f / (1.0f + expf(-s));
}

// ------------- edge_index convert (int64 auto-detect) ----------------------
__global__ __launch_bounds__(256) void convert_kernel(
    const int* __restrict__ w, int* __restrict__ src32,
    int* __restrict__ dst32, int E)
{
    __shared__ int flag;
    if (threadIdx.x == 0) {
        int z = 0;
        for (int k = 0; k < 64; k++) z |= w[2 * k + 1];
        flag = (z == 0) ? 1 : 0;   // all odd words zero => int64 layout
    }
    __syncthreads();
    int i64 = flag;
    int total = 2 * E;
    int stride = gridDim.x * blockDim.x;
    for (int i = blockIdx.x * blockDim.x + threadIdx.x; i < total; i += stride) {
        int v = i64 ? w[2 * i] : w[i];   // little-endian low word
        if (i < E) src32[i] = v; else dst32[i - E] = v;
    }
}

// ------------------------- degree histogram --------------------------------
__global__ __launch_bounds__(256) void hist_kernel(
    const int* __restrict__ dst32, int* __restrict__ counts, int E)
{
    int stride = gridDim.x * blockDim.x;
    for (int e = blockIdx.x * blockDim.x + threadIdx.x; e < E; e += stride)
        atomicAdd(&counts[dst32[e]], 1);
}

__global__ __launch_bounds__(256) void dinv_kernel(
    const int* __restrict__ counts, float* __restrict__ dinv, int N)
{
    int i = blockIdx.x * blockDim.x + threadIdx.x;
    if (i < N) dinv[i] = rsqrtf((float)counts[i] + 1.0f);
}

// --------------- exclusive scan (single block, wave shuffles) --------------
__global__ __launch_bounds__(1024) void scan_kernel(
    const int* __restrict__ counts, int* __restrict__ offsets,
    int* __restrict__ cursor, int N)
{
    __shared__ int wsum[16];
    __shared__ int wpre[16];
    int t = threadIdx.x;
    int lane = t & 63;
    int wid = t >> 6;
    int carry = 0;
    for (int base = 0; base < N; base += 1024) {
        int i = base + t;
        int v = (i < N) ? counts[i] : 0;
        int s = v;
        #pragma unroll
        for (int off = 1; off < 64; off <<= 1) {
            int n = __shfl_up(s, off);
            if (lane >= off) s += n;
        }
        if (lane == 63) wsum[wid] = s;
        __syncthreads();
        if (t < 16) {
            int ws = wsum[t];
            #pragma unroll
            for (int off = 1; off < 16; off <<= 1) {
                int n = __shfl_up(ws, off);
                if (t >= off) ws += n;
            }
            wpre[t] = ws;
        }
        __syncthreads();
        int wex = wid ? wpre[wid - 1] : 0;
        int excl = carry + wex + (s - v);
        if (i < N) { offsets[i] = excl; cursor[i] = excl; }
        carry += wpre[15];
        __syncthreads();
    }
    if (t == 0) offsets[N] = carry;
}

// -------------------- bucket edges by dst (CSR) ----------------------------
__global__ __launch_bounds__(256) void bucket_kernel(
    const int* __restrict__ src32, const int* __restrict__ dst32,
    const float* __restrict__ dinv, int* __restrict__ cursor,
    int2* __restrict__ edges, int E)
{
    int stride = gridDim.x * blockDim.x;
    for (int e = blockIdx.x * blockDim.x + threadIdx.x; e < E; e += stride) {
        int s = src32[e];
        int d = dst32[e];
        int pos = atomicAdd(&cursor[d], 1);
        edges[pos] = make_int2(s, __float_as_int(dinv[s] * dinv[d]));
    }
}

// --------------------------- fp32 GEMM -------------------------------------
// H[M,128] = X[M,128] @ W[128,128]; BM=64 rows/block, BK=32, 256 threads
// thread (tx 0..15, ty 0..15): cols {4tx..4tx+3, 64+4tx..}, rows ty*4..+3
#define BM 64
#define BK 32
#define XPAD 36
__global__ __launch_bounds__(256) void gemm_kernel(
    const float* __restrict__ X, const float* __restrict__ W,
    float* __restrict__ H, int M)
{
    __shared__ float Ws[BK * D];        // [32][128]
    __shared__ float Xs[BM * XPAD];     // [64][36] (pad: conflict-free b32)
    int tid = threadIdx.x;
    int tx = tid & 15;
    int ty = tid >> 4;
    int rowbase = blockIdx.x * BM;

    float4 acc0[4], acc1[4];
    #pragma unroll
    for (int r = 0; r < 4; r++) {
        acc0[r] = make_float4(0.f, 0.f, 0.f, 0.f);
        acc1[r] = make_float4(0.f, 0.f, 0.f, 0.f);
    }

    for (int k0 = 0; k0 < D; k0 += BK) {
        // stage W chunk: 1024 float4, 4 per thread, coalesced
        #pragma unroll
        for (int i = 0; i < 4; i++) {
            int f = tid + i * 256;
            int kk = f >> 5;
            int c4 = (f & 31) << 2;
            float4 wv = *(const float4*)(W + (size_t)(k0 + kk) * D + c4);
            *(float4*)(&Ws[kk * D + c4]) = wv;
        }
        // stage X chunk: 512 float4, 2 per thread, coalesced
        #pragma unroll
        for (int i = 0; i < 2; i++) {
            int f = tid + i * 256;
            int r = f >> 3;
            int c4 = (f & 7) << 2;
            int row = rowbase + r;
            float4 xv = make_float4(0.f, 0.f, 0.f, 0.f);
            if (row < M) xv = *(const float4*)(X + (size_t)row * D + k0 + c4);
            *(float4*)(&Xs[r * XPAD + c4]) = xv;
        }
        __syncthreads();
        #pragma unroll
        for (int kk = 0; kk < BK; kk++) {
            float4 w0 = *(const float4*)(&Ws[kk * D + 4 * tx]);
            float4 w1 = *(const float4*)(&Ws[kk * D + 64 + 4 * tx]);
            #pragma unroll
            for (int r = 0; r < 4; r++) {
                float xv = Xs[(ty * 4 + r) * XPAD + kk];
                acc0[r].x += xv * w0.x;
                acc0[r].y += xv * w0.y;
                acc0[r].z += xv * w0.z;
                acc0[r].w += xv * w0.w;
                acc1[r].x += xv * w1.x;
                acc1[r].y += xv * w1.y;
                acc1[r].z += xv * w1.z;
                acc1[r].w += xv * w1.w;
            }
        }
        __syncthreads();
    }
    #pragma unroll
    for (int r = 0; r < 4; r++) {
        int row = rowbase + ty * 4 + r;
        if (row < M) {
            *(float4*)(H + (size_t)row * D + 4 * tx) = acc0[r];
            *(float4*)(H + (size_t)row * D + 64 + 4 * tx) = acc1[r];
        }
    }
}

// ------------------- per-node aggregation (1 wave/node) --------------------
// lanes: 64 x float2 = 128 features. out = relu(sum + h*dinv^2 + b) * gate
__global__ __launch_bounds__(256) void agg_kernel(
    const float* __restrict__ H, const int2* __restrict__ edges,
    const int* __restrict__ offsets, const float* __restrict__ dinv,
    const float* __restrict__ bias, const float* __restrict__ gate,
    float* __restrict__ out, int M)
{
    int wid = threadIdx.x >> 6;
    int lane = threadIdx.x & 63;
    int node = blockIdx.x * 4 + wid;
    if (node >= M) return;

    int beg = offsets[node];
    int end = offsets[node + 1];
    float ax = 0.f, ay = 0.f;
    for (int j = beg; j < end; j++) {
        int2 ep = edges[j];                      // wave-uniform load
        float nv = __int_as_float(ep.y);
        float2 hv = *(const float2*)(H + (size_t)ep.x * D + lane * 2);
        ax += hv.x * nv;
        ay += hv.y * nv;
    }
    float di = dinv[node];
    float sn = di * di;                          // 1/deg
    float2 hs = *(const float2*)(H + (size_t)node * D + lane * 2);
    ax += hs.x * sn;
    ay += hs.y * sn;
    float2 bv = *(const float2*)(bias + lane * 2);
    float2 gv = *(const float2*)(gate + lane * 2);
    ax = fmaxf(ax + bv.x, 0.f) * gv.x;
    ay = fmaxf(ay + bv.y, 0.f) * gv.y;
    *(float2*)(out + (size_t)node * D + lane * 2) = make_float2(ax, ay);
}

// ---------------------------------------------------------------------------
static inline size_t align_up(size_t v, size_t a) { return (v + a - 1) & ~(a - 1); }

extern "C" void kernel_launch(void* const* d_in, const int* in_sizes, int n_in,
                              void* d_out, int out_size, void* d_ws, size_t ws_size,
                              hipStream_t stream)
{
    const float* x   = (const float*)d_in[0];
    const int*   ei  = (const int*)d_in[1];   // int32 or int64 (auto-detected)
    const float* ts  = (const float*)d_in[2];
    const float* Wl[3] = { (const float*)d_in[3], (const float*)d_in[5], (const float*)d_in[7] };
    const float* bl[3] = { (const float*)d_in[4], (const float*)d_in[6], (const float*)d_in[8] };
    const float* Wg1 = (const float*)d_in[9];
    const float* bg1 = (const float*)d_in[10];
    const float* Wg2 = (const float*)d_in[11];
    const float* bg2 = (const float*)d_in[12];

    const int N = in_sizes[0] / D;      // 100000
    const int E = in_sizes[1] / 2;      // 600000

    // workspace carve (all 256B aligned)
    char* p = (char*)d_ws;
    float* h    = (float*)p; p += align_up((size_t)N * D * 4, 256);
    float* buf0 = (float*)p; p += align_up((size_t)N * D * 4, 256);
    int* src32  = (int*)p;   p += align_up((size_t)E * 4, 256);
    int* dst32  = (int*)p;   p += align_up((size_t)E * 4, 256);
    int* counts = (int*)p;   p += align_up((size_t)N * 4, 256);
    float* dinv = (float*)p; p += align_up((size_t)N * 4, 256);
    int* offs   = (int*)p;   p += align_up((size_t)(N + 1) * 4, 256);
    int* cursor = (int*)p;   p += align_up((size_t)N * 4, 256);
    int2* edges = (int2*)p;  p += align_up((size_t)E * 8, 256);
    float* gate = (float*)p; p += align_up((size_t)D * 4, 256);
    (void)ws_size; (void)n_in; (void)out_size;

    hipMemsetAsync(counts, 0, (size_t)N * 4, stream);
    gate_kernel<<<1, 128, 0, stream>>>(ts, Wg1, bg1, Wg2, bg2, gate);
    convert_kernel<<<1024, 256, 0, stream>>>(ei, src32, dst32, E);
    hist_kernel<<<1024, 256, 0, stream>>>(dst32, counts, E);
    dinv_kernel<<<(N + 255) / 256, 256, 0, stream>>>(counts, dinv, N);
    scan_kernel<<<1, 1024, 0, stream>>>(counts, offs, cursor, N);
    bucket_kernel<<<1024, 256, 0, stream>>>(src32, dst32, dinv, cursor, edges, E);

    const float* xin = x;
    float* outs[3] = { buf0, buf0, (float*)d_out };
    for (int l = 0; l < 3; l++) {
        gemm_kernel<<<(N + BM - 1) / BM, 256, 0, stream>>>(xin, Wl[l], h, N);
        agg_kernel<<<(N + 3) / 4, 256, 0, stream>>>(h, edges, offs, dinv,
                                                    bl[l], gate, outs[l], N);
        xin = outs[l];
    }
}

// Round 2
// 557.003 us; speedup vs baseline: 1.1704x; 1.1704x over previous
//
#include <hip/hip_runtime.h>
#include <hip/hip_bf16.h>
#include <math.h>

// ---------------------------------------------------------------------------
// DynamicGCN: 3x (GCNConv -> ReLU -> *gate)
// R1 changes: multi-block scan (was 92us mono-block), hist fused into
// convert, dinv folded into scan phase C.
// ---------------------------------------------------------------------------

#define D 128   // feature dim (D_IN == HID == 128)

// ---------------- gate: sigmoid(tanh(t*Wg1+bg1)@Wg2+bg2) -------------------
__global__ __launch_bounds__(128) void gate_kernel(
    const float* __restrict__ t, const float* __restrict__ Wg1,
    const float* __restrict__ bg1, const float* __restrict__ Wg2,
    const float* __restrict__ bg2, float* __restrict__ gate)
{
    __shared__ float u[D];
    int j = threadIdx.x;
    float tv = t[0];
    u[j] = tanhf(tv * Wg1[j] + bg1[j]);
    __syncthreads();
    float s = bg2[j];
    #pragma unroll 8
    for (int k = 0; k < D; k++) s += u[k] * Wg2[k * D + j];
    gate[j] = 1.0f / (1.0f + expf(-s));
}

// ---- edge_index convert (int64 auto-detect) + fused degree histogram ------
__global__ __launch_bounds__(256) void convert_hist_kernel(
    const int* __restrict__ w, int* __restrict__ src32,
    int* __restrict__ dst32, int* __restrict__ counts, int E)
{
    __shared__ int flag;
    if (threadIdx.x == 0) {
        int z = 0;
        for (int k = 0; k < 64; k++) z |= w[2 * k + 1];
        flag = (z == 0) ? 1 : 0;   // all odd words zero => int64 layout
    }
    __syncthreads();
    int i64 = flag;
    int total = 2 * E;
    int stride = gridDim.x * blockDim.x;
    for (int i = blockIdx.x * blockDim.x + threadIdx.x; i < total; i += stride) {
        int v = i64 ? w[2 * i] : w[i];   // little-endian low word
        if (i < E) {
            src32[i] = v;
        } else {
            dst32[i - E] = v;
            atomicAdd(&counts[v], 1);
        }
    }
}

// ------------------- multi-block exclusive scan ----------------------------
// Phase A: per-block (1024-elem chunk) sums. Phase B: scan block sums (<=1024
// blocks, one workgroup). Phase C: final per-element exclusive scan + cursor
// init + dinv = rsqrt(deg+1).
#define SCHUNK 1024
__global__ __launch_bounds__(256) void scan_partial_kernel(
    const int* __restrict__ counts, int* __restrict__ bsums, int N)
{
    int base = blockIdx.x * SCHUNK + threadIdx.x * 4;
    int s = 0;
    if (base + 3 < N) {
        int4 v = *(const int4*)(counts + base);
        s = v.x + v.y + v.z + v.w;
    } else {
        for (int k = 0; k < 4; k++) if (base + k < N) s += counts[base + k];
    }
    #pragma unroll
    for (int off = 1; off < 64; off <<= 1) s += __shfl_xor(s, off);
    __shared__ int wsum[4];
    int lane = threadIdx.x & 63, wid = threadIdx.x >> 6;
    if (lane == 0) wsum[wid] = s;
    __syncthreads();
    if (threadIdx.x == 0)
        bsums[blockIdx.x] = wsum[0] + wsum[1] + wsum[2] + wsum[3];
}

__global__ __launch_bounds__(1024) void scan_bsums_kernel(
    int* __restrict__ bsums, int* __restrict__ total_out, int B)
{
    int t = threadIdx.x;
    int v = (t < B) ? bsums[t] : 0;
    int lane = t & 63, wid = t >> 6;
    int s = v;
    #pragma unroll
    for (int off = 1; off < 64; off <<= 1) {
        int n = __shfl_up(s, off);
        if (lane >= off) s += n;
    }
    __shared__ int wsum[16], wpre[16];
    if (lane == 63) wsum[wid] = s;
    __syncthreads();
    if (t < 16) {
        int ws = wsum[t];
        #pragma unroll
        for (int off = 1; off < 16; off <<= 1) {
            int n = __shfl_up(ws, off);
            if (t >= off) ws += n;
        }
        wpre[t] = ws;
    }
    __syncthreads();
    int wex = wid ? wpre[wid - 1] : 0;
    if (t < B) bsums[t] = wex + (s - v);      // exclusive
    if (t == 0) *total_out = wpre[15];        // grand total -> offsets[N]
}

__global__ __launch_bounds__(256) void scan_final_kernel(
    const int* __restrict__ counts, const int* __restrict__ bsums,
    int* __restrict__ offsets, int* __restrict__ cursor,
    float* __restrict__ dinv, int N)
{
    int base = blockIdx.x * SCHUNK + threadIdx.x * 4;
    int4 v = make_int4(0, 0, 0, 0);
    bool full = (base + 3 < N);
    if (full) v = *(const int4*)(counts + base);
    else {
        if (base + 0 < N) v.x = counts[base + 0];
        if (base + 1 < N) v.y = counts[base + 1];
        if (base + 2 < N) v.z = counts[base + 2];
        if (base + 3 < N) v.w = counts[base + 3];
    }
    int sum = v.x + v.y + v.z + v.w;
    int lane = threadIdx.x & 63, wid = threadIdx.x >> 6;
    int s = sum;
    #pragma unroll
    for (int off = 1; off < 64; off <<= 1) {
        int n = __shfl_up(s, off);
        if (lane >= off) s += n;
    }
    __shared__ int wsum[4], wpre[4];
    if (lane == 63) wsum[wid] = s;
    __syncthreads();
    if (threadIdx.x == 0) {
        int a = 0;
        #pragma unroll
        for (int k = 0; k < 4; k++) { wpre[k] = a; a += wsum[k]; }
    }
    __syncthreads();
    int e0 = bsums[blockIdx.x] + wpre[wid] + (s - sum);
    int4 o = make_int4(e0, e0 + v.x, e0 + v.x + v.y, e0 + v.x + v.y + v.z);
    float4 dv = make_float4(rsqrtf((float)v.x + 1.f), rsqrtf((float)v.y + 1.f),
                            rsqrtf((float)v.z + 1.f), rsqrtf((float)v.w + 1.f));
    if (full) {
        *(int4*)(offsets + base) = o;
        *(int4*)(cursor + base) = o;
        *(float4*)(dinv + base) = dv;
    } else {
        int oo[4] = { o.x, o.y, o.z, o.w };
        float dd[4] = { dv.x, dv.y, dv.z, dv.w };
        for (int k = 0; k < 4; k++)
            if (base + k < N) {
                offsets[base + k] = oo[k];
                cursor[base + k] = oo[k];
                dinv[base + k] = dd[k];
            }
    }
}

// -------------------- bucket edges by dst (CSR) ----------------------------
__global__ __launch_bounds__(256) void bucket_kernel(
    const int* __restrict__ src32, const int* __restrict__ dst32,
    const float* __restrict__ dinv, int* __restrict__ cursor,
    int2* __restrict__ edges, int E)
{
    int stride = gridDim.x * blockDim.x;
    for (int e = blockIdx.x * blockDim.x + threadIdx.x; e < E; e += stride) {
        int s = src32[e];
        int d = dst32[e];
        int pos = atomicAdd(&cursor[d], 1);
        edges[pos] = make_int2(s, __float_as_int(dinv[s] * dinv[d]));
    }
}

// --------------------------- fp32 GEMM -------------------------------------
// H[M,128] = X[M,128] @ W[128,128]; BM=64 rows/block, BK=32, 256 threads
#define BM 64
#define BK 32
#define XPAD 36
__global__ __launch_bounds__(256) void gemm_kernel(
    const float* __restrict__ X, const float* __restrict__ W,
    float* __restrict__ H, int M)
{
    __shared__ float Ws[BK * D];        // [32][128]
    __shared__ float Xs[BM * XPAD];     // [64][36]
    int tid = threadIdx.x;
    int tx = tid & 15;
    int ty = tid >> 4;
    int rowbase = blockIdx.x * BM;

    float4 acc0[4], acc1[4];
    #pragma unroll
    for (int r = 0; r < 4; r++) {
        acc0[r] = make_float4(0.f, 0.f, 0.f, 0.f);
        acc1[r] = make_float4(0.f, 0.f, 0.f, 0.f);
    }

    for (int k0 = 0; k0 < D; k0 += BK) {
        #pragma unroll
        for (int i = 0; i < 4; i++) {
            int f = tid + i * 256;
            int kk = f >> 5;
            int c4 = (f & 31) << 2;
            float4 wv = *(const float4*)(W + (size_t)(k0 + kk) * D + c4);
            *(float4*)(&Ws[kk * D + c4]) = wv;
        }
        #pragma unroll
        for (int i = 0; i < 2; i++) {
            int f = tid + i * 256;
            int r = f >> 3;
            int c4 = (f & 7) << 2;
            int row = rowbase + r;
            float4 xv = make_float4(0.f, 0.f, 0.f, 0.f);
            if (row < M) xv = *(const float4*)(X + (size_t)row * D + k0 + c4);
            *(float4*)(&Xs[r * XPAD + c4]) = xv;
        }
        __syncthreads();
        #pragma unroll
        for (int kk = 0; kk < BK; kk++) {
            float4 w0 = *(const float4*)(&Ws[kk * D + 4 * tx]);
            float4 w1 = *(const float4*)(&Ws[kk * D + 64 + 4 * tx]);
            #pragma unroll
            for (int r = 0; r < 4; r++) {
                float xv = Xs[(ty * 4 + r) * XPAD + kk];
                acc0[r].x += xv * w0.x;
                acc0[r].y += xv * w0.y;
                acc0[r].z += xv * w0.z;
                acc0[r].w += xv * w0.w;
                acc1[r].x += xv * w1.x;
                acc1[r].y += xv * w1.y;
                acc1[r].z += xv * w1.z;
                acc1[r].w += xv * w1.w;
            }
        }
        __syncthreads();
    }
    #pragma unroll
    for (int r = 0; r < 4; r++) {
        int row = rowbase + ty * 4 + r;
        if (row < M) {
            *(float4*)(H + (size_t)row * D + 4 * tx) = acc0[r];
            *(float4*)(H + (size_t)row * D + 64 + 4 * tx) = acc1[r];
        }
    }
}

// ------------------- per-node aggregation (1 wave/node) --------------------
__global__ __launch_bounds__(256) void agg_kernel(
    const float* __restrict__ H, const int2* __restrict__ edges,
    const int* __restrict__ offsets, const float* __restrict__ dinv,
    const float* __restrict__ bias, const float* __restrict__ gate,
    float* __restrict__ out, int M)
{
    int wid = threadIdx.x >> 6;
    int lane = threadIdx.x & 63;
    int node = blockIdx.x * 4 + wid;
    if (node >= M) return;

    int beg = offsets[node];
    int end = offsets[node + 1];
    float ax = 0.f, ay = 0.f;
    for (int j = beg; j < end; j++) {
        int2 ep = edges[j];                      // wave-uniform load
        float nv = __int_as_float(ep.y);
        float2 hv = *(const float2*)(H + (size_t)ep.x * D + lane * 2);
        ax += hv.x * nv;
        ay += hv.y * nv;
    }
    float di = dinv[node];
    float sn = di * di;                          // 1/deg
    float2 hs = *(const float2*)(H + (size_t)node * D + lane * 2);
    ax += hs.x * sn;
    ay += hs.y * sn;
    float2 bv = *(const float2*)(bias + lane * 2);
    float2 gv = *(const float2*)(gate + lane * 2);
    ax = fmaxf(ax + bv.x, 0.f) * gv.x;
    ay = fmaxf(ay + bv.y, 0.f) * gv.y;
    *(float2*)(out + (size_t)node * D + lane * 2) = make_float2(ax, ay);
}

// ---------------------------------------------------------------------------
static inline size_t align_up(size_t v, size_t a) { return (v + a - 1) & ~(a - 1); }

extern "C" void kernel_launch(void* const* d_in, const int* in_sizes, int n_in,
                              void* d_out, int out_size, void* d_ws, size_t ws_size,
                              hipStream_t stream)
{
    const float* x   = (const float*)d_in[0];
    const int*   ei  = (const int*)d_in[1];   // int32 or int64 (auto-detected)
    const float* ts  = (const float*)d_in[2];
    const float* Wl[3] = { (const float*)d_in[3], (const float*)d_in[5], (const float*)d_in[7] };
    const float* bl[3] = { (const float*)d_in[4], (const float*)d_in[6], (const float*)d_in[8] };
    const float* Wg1 = (const float*)d_in[9];
    const float* bg1 = (const float*)d_in[10];
    const float* Wg2 = (const float*)d_in[11];
    const float* bg2 = (const float*)d_in[12];

    const int N = in_sizes[0] / D;      // 100000
    const int E = in_sizes[1] / 2;      // 600000
    const int NB = (N + SCHUNK - 1) / SCHUNK;   // scan blocks (98)

    // workspace carve (all 256B aligned)
    char* p = (char*)d_ws;
    float* h    = (float*)p; p += align_up((size_t)N * D * 4, 256);
    float* buf0 = (float*)p; p += align_up((size_t)N * D * 4, 256);
    int* src32  = (int*)p;   p += align_up((size_t)E * 4, 256);
    int* dst32  = (int*)p;   p += align_up((size_t)E * 4, 256);
    int* counts = (int*)p;   p += align_up((size_t)N * 4, 256);
    float* dinv = (float*)p; p += align_up((size_t)N * 4, 256);
    int* offs   = (int*)p;   p += align_up((size_t)(N + 1) * 4, 256);
    int* cursor = (int*)p;   p += align_up((size_t)N * 4, 256);
    int2* edges = (int2*)p;  p += align_up((size_t)E * 8, 256);
    float* gate = (float*)p; p += align_up((size_t)D * 4, 256);
    int* bsums  = (int*)p;   p += align_up((size_t)NB * 4, 256);
    (void)ws_size; (void)n_in; (void)out_size;

    hipMemsetAsync(counts, 0, (size_t)N * 4, stream);
    gate_kernel<<<1, 128, 0, stream>>>(ts, Wg1, bg1, Wg2, bg2, gate);
    convert_hist_kernel<<<1024, 256, 0, stream>>>(ei, src32, dst32, counts, E);
    scan_partial_kernel<<<NB, 256, 0, stream>>>(counts, bsums, N);
    scan_bsums_kernel<<<1, 1024, 0, stream>>>(bsums, offs + N, NB);
    scan_final_kernel<<<NB, 256, 0, stream>>>(counts, bsums, offs, cursor, dinv, N);
    bucket_kernel<<<1024, 256, 0, stream>>>(src32, dst32, dinv, cursor, edges, E);

    const float* xin = x;
    float* outs[3] = { buf0, buf0, (float*)d_out };
    for (int l = 0; l < 3; l++) {
        gemm_kernel<<<(N + BM - 1) / BM, 256, 0, stream>>>(xin, Wl[l], h, N);
        agg_kernel<<<(N + 3) / 4, 256, 0, stream>>>(h, edges, offs, dinv,
                                                    bl[l], gate, outs[l], N);
        xin = outs[l];
    }
}

// Round 3
// 503.176 us; speedup vs baseline: 1.2957x; 1.1070x over previous
//
#include <hip/hip_runtime.h>
#include <hip/hip_bf16.h>
#include <math.h>

// ---------------------------------------------------------------------------
// DynamicGCN: 3x (GCNConv -> ReLU -> *gate)
// R1: multi-block scan, hist fused into convert, dinv folded into scan C.
// R2: split-bf16 MFMA GEMM (hi*hi + hi*lo + lo*hi), W pre-swizzled into
//     B-fragment order once -> coalesced L2 frag loads, no LDS.
// ---------------------------------------------------------------------------

#define D 128   // feature dim (D_IN == HID == 128)

typedef __attribute__((ext_vector_type(8))) short short8;
typedef __attribute__((ext_vector_type(4))) float floatx4;

__device__ __forceinline__ unsigned bf16_rne(float x) {
    unsigned u = __float_as_uint(x);
    return (u + 0x7FFFu + ((u >> 16) & 1u)) >> 16;
}

// ---------------- gate: sigmoid(tanh(t*Wg1+bg1)@Wg2+bg2) -------------------
__global__ __launch_bounds__(128) void gate_kernel(
    const float* __restrict__ t, const float* __restrict__ Wg1,
    const float* __restrict__ bg1, const float* __restrict__ Wg2,
    const float* __restrict__ bg2, float* __restrict__ gate)
{
    __shared__ float u[D];
    int j = threadIdx.x;
    float tv = t[0];
    u[j] = tanhf(tv * Wg1[j] + bg1[j]);
    __syncthreads();
    float s = bg2[j];
    #pragma unroll 8
    for (int k = 0; k < D; k++) s += u[k] * Wg2[k * D + j];
    gate[j] = 1.0f / (1.0f + expf(-s));
}

// ---- edge_index convert (int64 auto-detect) + fused degree histogram ------
__global__ __launch_bounds__(256) void convert_hist_kernel(
    const int* __restrict__ w, int* __restrict__ src32,
    int* __restrict__ dst32, int* __restrict__ counts, int E)
{
    __shared__ int flag;
    if (threadIdx.x == 0) {
        int z = 0;
        for (int k = 0; k < 64; k++) z |= w[2 * k + 1];
        flag = (z == 0) ? 1 : 0;   // all odd words zero => int64 layout
    }
    __syncthreads();
    int i64 = flag;
    int total = 2 * E;
    int stride = gridDim.x * blockDim.x;
    for (int i = blockIdx.x * blockDim.x + threadIdx.x; i < total; i += stride) {
        int v = i64 ? w[2 * i] : w[i];   // little-endian low word
        if (i < E) {
            src32[i] = v;
        } else {
            dst32[i - E] = v;
            atomicAdd(&counts[v], 1);
        }
    }
}

// ------------------- multi-block exclusive scan ----------------------------
#define SCHUNK 1024
__global__ __launch_bounds__(256) void scan_partial_kernel(
    const int* __restrict__ counts, int* __restrict__ bsums, int N)
{
    int base = blockIdx.x * SCHUNK + threadIdx.x * 4;
    int s = 0;
    if (base + 3 < N) {
        int4 v = *(const int4*)(counts + base);
        s = v.x + v.y + v.z + v.w;
    } else {
        for (int k = 0; k < 4; k++) if (base + k < N) s += counts[base + k];
    }
    #pragma unroll
    for (int off = 1; off < 64; off <<= 1) s += __shfl_xor(s, off);
    __shared__ int wsum[4];
    int lane = threadIdx.x & 63, wid = threadIdx.x >> 6;
    if (lane == 0) wsum[wid] = s;
    __syncthreads();
    if (threadIdx.x == 0)
        bsums[blockIdx.x] = wsum[0] + wsum[1] + wsum[2] + wsum[3];
}

__global__ __launch_bounds__(1024) void scan_bsums_kernel(
    int* __restrict__ bsums, int* __restrict__ total_out, int B)
{
    int t = threadIdx.x;
    int v = (t < B) ? bsums[t] : 0;
    int lane = t & 63, wid = t >> 6;
    int s = v;
    #pragma unroll
    for (int off = 1; off < 64; off <<= 1) {
        int n = __shfl_up(s, off);
        if (lane >= off) s += n;
    }
    __shared__ int wsum[16], wpre[16];
    if (lane == 63) wsum[wid] = s;
    __syncthreads();
    if (t < 16) {
        int ws = wsum[t];
        #pragma unroll
        for (int off = 1; off < 16; off <<= 1) {
            int n = __shfl_up(ws, off);
            if (t >= off) ws += n;
        }
        wpre[t] = ws;
    }
    __syncthreads();
    int wex = wid ? wpre[wid - 1] : 0;
    if (t < B) bsums[t] = wex + (s - v);      // exclusive
    if (t == 0) *total_out = wpre[15];        // grand total -> offsets[N]
}

__global__ __launch_bounds__(256) void scan_final_kernel(
    const int* __restrict__ counts, const int* __restrict__ bsums,
    int* __restrict__ offsets, int* __restrict__ cursor,
    float* __restrict__ dinv, int N)
{
    int base = blockIdx.x * SCHUNK + threadIdx.x * 4;
    int4 v = make_int4(0, 0, 0, 0);
    bool full = (base + 3 < N);
    if (full) v = *(const int4*)(counts + base);
    else {
        if (base + 0 < N) v.x = counts[base + 0];
        if (base + 1 < N) v.y = counts[base + 1];
        if (base + 2 < N) v.z = counts[base + 2];
        if (base + 3 < N) v.w = counts[base + 3];
    }
    int sum = v.x + v.y + v.z + v.w;
    int lane = threadIdx.x & 63, wid = threadIdx.x >> 6;
    int s = sum;
    #pragma unroll
    for (int off = 1; off < 64; off <<= 1) {
        int n = __shfl_up(s, off);
        if (lane >= off) s += n;
    }
    __shared__ int wsum[4], wpre[4];
    if (lane == 63) wsum[wid] = s;
    __syncthreads();
    if (threadIdx.x == 0) {
        int a = 0;
        #pragma unroll
        for (int k = 0; k < 4; k++) { wpre[k] = a; a += wsum[k]; }
    }
    __syncthreads();
    int e0 = bsums[blockIdx.x] + wpre[wid] + (s - sum);
    int4 o = make_int4(e0, e0 + v.x, e0 + v.x + v.y, e0 + v.x + v.y + v.z);
    float4 dv = make_float4(rsqrtf((float)v.x + 1.f), rsqrtf((float)v.y + 1.f),
                            rsqrtf((float)v.z + 1.f), rsqrtf((float)v.w + 1.f));
    if (full) {
        *(int4*)(offsets + base) = o;
        *(int4*)(cursor + base) = o;
        *(float4*)(dinv + base) = dv;
    } else {
        int oo[4] = { o.x, o.y, o.z, o.w };
        float dd[4] = { dv.x, dv.y, dv.z, dv.w };
        for (int k = 0; k < 4; k++)
            if (base + k < N) {
                offsets[base + k] = oo[k];
                cursor[base + k] = oo[k];
                dinv[base + k] = dd[k];
            }
    }
}

// -------------------- bucket edges by dst (CSR) ----------------------------
__global__ __launch_bounds__(256) void bucket_kernel(
    const int* __restrict__ src32, const int* __restrict__ dst32,
    const float* __restrict__ dinv, int* __restrict__ cursor,
    int2* __restrict__ edges, int E)
{
    int stride = gridDim.x * blockDim.x;
    for (int e = blockIdx.x * blockDim.x + threadIdx.x; e < E; e += stride) {
        int s = src32[e];
        int d = dst32[e];
        int pos = atomicAdd(&cursor[d], 1);
        edges[pos] = make_int2(s, __float_as_int(dinv[s] * dinv[d]));
    }
}

// ---------------- W pre-swizzle to MFMA B-fragment order -------------------
// B-frag for 16x16x32 bf16: lane holds B[k=(lane>>4)*8+j][n=lane&15], j=0..7.
// Fragment index f = ((kc*8 + n)*64 + lane); 2048 frags/layer, 16 B each.
__global__ __launch_bounds__(256) void wswizzle_kernel(
    const float* __restrict__ W0, const float* __restrict__ W1,
    const float* __restrict__ W2, short8* __restrict__ Wf_hi,
    short8* __restrict__ Wf_lo)
{
    int f = blockIdx.x * 256 + threadIdx.x;   // 0..6143
    if (f >= 3 * 2048) return;
    int layer = f >> 11;
    int fi = f & 2047;
    int lane = fi & 63;
    int t = fi >> 6;                 // kc*8 + n
    int kc = t >> 3, n = t & 7;
    const float* W = (layer == 0) ? W0 : (layer == 1) ? W1 : W2;
    int krow = kc * 32 + (lane >> 4) * 8;
    int col = n * 16 + (lane & 15);
    short8 hv, lv;
    #pragma unroll
    for (int j = 0; j < 8; j++) {
        float x = W[(size_t)(krow + j) * D + col];
        unsigned hb = bf16_rne(x);
        float hf = __uint_as_float(hb << 16);
        unsigned lb = bf16_rne(x - hf);
        hv[j] = (short)hb;
        lv[j] = (short)lb;
    }
    Wf_hi[f] = hv;
    Wf_lo[f] = lv;
}

// ----------------- split-bf16 MFMA GEMM: H = X @ W -------------------------
// Block: 128 rows x 128 cols, 4 waves; wave w: rows [w*32, w*32+32).
// A loaded from global fp32 (converted in-reg), B frags from pre-swizzled W.
#define GBM 128
__device__ __forceinline__ void cvt8(const float* f, short8& hi, short8& lo) {
    #pragma unroll
    for (int j = 0; j < 8; j++) {
        unsigned hb = bf16_rne(f[j]);
        float hf = __uint_as_float(hb << 16);
        unsigned lb = bf16_rne(f[j] - hf);
        hi[j] = (short)hb;
        lo[j] = (short)lb;
    }
}

__global__ __launch_bounds__(256) void gemm_mfma_kernel(
    const float* __restrict__ X, const short8* __restrict__ Wf_hi,
    const short8* __restrict__ Wf_lo, float* __restrict__ H, int M)
{
    int tid = threadIdx.x;
    int w = tid >> 6, lane = tid & 63;
    int m16 = lane & 15, qd = lane >> 4;
    int rowbase = blockIdx.x * GBM + w * 32;
    int r0 = rowbase + m16;
    int r1 = r0 + 16;

    floatx4 acc[2][8];
    #pragma unroll
    for (int rt = 0; rt < 2; rt++)
        #pragma unroll
        for (int n = 0; n < 8; n++)
            acc[rt][n] = (floatx4)(0.f);

    #pragma unroll 1
    for (int kc = 0; kc < 4; kc++) {
        int kof = kc * 32 + qd * 8;
        float a0[8], a1[8];
        if (r0 < M) {
            *(float4*)(a0) = *(const float4*)(X + (size_t)r0 * D + kof);
            *(float4*)(a0 + 4) = *(const float4*)(X + (size_t)r0 * D + kof + 4);
        } else {
            #pragma unroll
            for (int j = 0; j < 8; j++) a0[j] = 0.f;
        }
        if (r1 < M) {
            *(float4*)(a1) = *(const float4*)(X + (size_t)r1 * D + kof);
            *(float4*)(a1 + 4) = *(const float4*)(X + (size_t)r1 * D + kof + 4);
        } else {
            #pragma unroll
            for (int j = 0; j < 8; j++) a1[j] = 0.f;
        }
        short8 ah[2], al[2];
        cvt8(a0, ah[0], al[0]);
        cvt8(a1, ah[1], al[1]);

        #pragma unroll
        for (int n = 0; n < 8; n++) {
            short8 bh = Wf_hi[(size_t)(kc * 8 + n) * 64 + lane];
            short8 bl = Wf_lo[(size_t)(kc * 8 + n) * 64 + lane];
            #pragma unroll
            for (int rt = 0; rt < 2; rt++) {
                acc[rt][n] = __builtin_amdgcn_mfma_f32_16x16x32_bf16(
                    ah[rt], bh, acc[rt][n], 0, 0, 0);
                acc[rt][n] = __builtin_amdgcn_mfma_f32_16x16x32_bf16(
                    ah[rt], bl, acc[rt][n], 0, 0, 0);
                acc[rt][n] = __builtin_amdgcn_mfma_f32_16x16x32_bf16(
                    al[rt], bh, acc[rt][n], 0, 0, 0);
            }
        }
    }

    // C/D layout: col = n*16 + (lane&15), row = rt*16 + (lane>>4)*4 + reg
    #pragma unroll
    for (int rt = 0; rt < 2; rt++) {
        #pragma unroll
        for (int reg = 0; reg < 4; reg++) {
            int row = rowbase + rt * 16 + qd * 4 + reg;
            if (row < M) {
                float* hp = H + (size_t)row * D + m16;
                #pragma unroll
                for (int n = 0; n < 8; n++)
                    hp[n * 16] = acc[rt][n][reg];
            }
        }
    }
}

// ------------------- per-node aggregation (1 wave/node) --------------------
__global__ __launch_bounds__(256) void agg_kernel(
    const float* __restrict__ H, const int2* __restrict__ edges,
    const int* __restrict__ offsets, const float* __restrict__ dinv,
    const float* __restrict__ bias, const float* __restrict__ gate,
    float* __restrict__ out, int M)
{
    int wid = threadIdx.x >> 6;
    int lane = threadIdx.x & 63;
    int node = blockIdx.x * 4 + wid;
    if (node >= M) return;

    int beg = offsets[node];
    int end = offsets[node + 1];
    float ax = 0.f, ay = 0.f;
    for (int j = beg; j < end; j++) {
        int2 ep = edges[j];                      // wave-uniform load
        float nv = __int_as_float(ep.y);
        float2 hv = *(const float2*)(H + (size_t)ep.x * D + lane * 2);
        ax += hv.x * nv;
        ay += hv.y * nv;
    }
    float di = dinv[node];
    float sn = di * di;                          // 1/deg
    float2 hs = *(const float2*)(H + (size_t)node * D + lane * 2);
    ax += hs.x * sn;
    ay += hs.y * sn;
    float2 bv = *(const float2*)(bias + lane * 2);
    float2 gv = *(const float2*)(gate + lane * 2);
    ax = fmaxf(ax + bv.x, 0.f) * gv.x;
    ay = fmaxf(ay + bv.y, 0.f) * gv.y;
    *(float2*)(out + (size_t)node * D + lane * 2) = make_float2(ax, ay);
}

// ---------------------------------------------------------------------------
static inline size_t align_up(size_t v, size_t a) { return (v + a - 1) & ~(a - 1); }

extern "C" void kernel_launch(void* const* d_in, const int* in_sizes, int n_in,
                              void* d_out, int out_size, void* d_ws, size_t ws_size,
                              hipStream_t stream)
{
    const float* x   = (const float*)d_in[0];
    const int*   ei  = (const int*)d_in[1];   // int32 or int64 (auto-detected)
    const float* ts  = (const float*)d_in[2];
    const float* Wl[3] = { (const float*)d_in[3], (const float*)d_in[5], (const float*)d_in[7] };
    const float* bl[3] = { (const float*)d_in[4], (const float*)d_in[6], (const float*)d_in[8] };
    const float* Wg1 = (const float*)d_in[9];
    const float* bg1 = (const float*)d_in[10];
    const float* Wg2 = (const float*)d_in[11];
    const float* bg2 = (const float*)d_in[12];

    const int N = in_sizes[0] / D;      // 100000
    const int E = in_sizes[1] / 2;      // 600000
    const int NB = (N + SCHUNK - 1) / SCHUNK;   // scan blocks

    // workspace carve (all 256B aligned)
    char* p = (char*)d_ws;
    float* h    = (float*)p; p += align_up((size_t)N * D * 4, 256);
    float* buf0 = (float*)p; p += align_up((size_t)N * D * 4, 256);
    int* src32  = (int*)p;   p += align_up((size_t)E * 4, 256);
    int* dst32  = (int*)p;   p += align_up((size_t)E * 4, 256);
    int* counts = (int*)p;   p += align_up((size_t)N * 4, 256);
    float* dinv = (float*)p; p += align_up((size_t)N * 4, 256);
    int* offs   = (int*)p;   p += align_up((size_t)(N + 1) * 4, 256);
    int* cursor = (int*)p;   p += align_up((size_t)N * 4, 256);
    int2* edges = (int2*)p;  p += align_up((size_t)E * 8, 256);
    float* gate = (float*)p; p += align_up((size_t)D * 4, 256);
    int* bsums  = (int*)p;   p += align_up((size_t)NB * 4, 256);
    short8* Wf_hi = (short8*)p; p += align_up((size_t)3 * 2048 * 16, 256);
    short8* Wf_lo = (short8*)p; p += align_up((size_t)3 * 2048 * 16, 256);
    (void)ws_size; (void)n_in; (void)out_size;

    hipMemsetAsync(counts, 0, (size_t)N * 4, stream);
    gate_kernel<<<1, 128, 0, stream>>>(ts, Wg1, bg1, Wg2, bg2, gate);
    wswizzle_kernel<<<24, 256, 0, stream>>>(Wl[0], Wl[1], Wl[2], Wf_hi, Wf_lo);
    convert_hist_kernel<<<1024, 256, 0, stream>>>(ei, src32, dst32, counts, E);
    scan_partial_kernel<<<NB, 256, 0, stream>>>(counts, bsums, N);
    scan_bsums_kernel<<<1, 1024, 0, stream>>>(bsums, offs + N, NB);
    scan_final_kernel<<<NB, 256, 0, stream>>>(counts, bsums, offs, cursor, dinv, N);
    bucket_kernel<<<1024, 256, 0, stream>>>(src32, dst32, dinv, cursor, edges, E);

    const float* xin = x;
    float* outs[3] = { buf0, buf0, (float*)d_out };
    for (int l = 0; l < 3; l++) {
        gemm_mfma_kernel<<<(N + GBM - 1) / GBM, 256, 0, stream>>>(
            xin, Wf_hi + (size_t)l * 2048, Wf_lo + (size_t)l * 2048, h, N);
        agg_kernel<<<(N + 3) / 4, 256, 0, stream>>>(h, edges, offs, dinv,
                                                    bl[l], gate, outs[l], N);
        xin = outs[l];
    }
}

// Round 4
// 425.404 us; speedup vs baseline: 1.5325x; 1.1828x over previous
//
#include <hip/hip_runtime.h>
#include <hip/hip_bf16.h>
#include <math.h>

// ---------------------------------------------------------------------------
// DynamicGCN: 3x (GCNConv -> ReLU -> *gate)
// R1: multi-block scan, hist fused into convert, dinv folded into scan C.
// R2: split-bf16 MFMA GEMM, W pre-swizzled into B-fragment order.
// R3: gemm A-path staged via global_load_lds (coalesced, XOR-swizzled LDS);
//     agg restructured for MLP: 2 nodes/wave (float4 lanes) + 4-deep unroll.
// ---------------------------------------------------------------------------

#define D 128   // feature dim (D_IN == HID == 128)

typedef __attribute__((ext_vector_type(8))) short short8;
typedef __attribute__((ext_vector_type(4))) float floatx4;

__device__ __forceinline__ unsigned bf16_rne(float x) {
    unsigned u = __float_as_uint(x);
    return (u + 0x7FFFu + ((u >> 16) & 1u)) >> 16;
}

__device__ __forceinline__ void gload_lds16(const float* g, float* l) {
    __builtin_amdgcn_global_load_lds(
        (const __attribute__((address_space(1))) unsigned int*)g,
        (__attribute__((address_space(3))) unsigned int*)l, 16, 0, 0);
}

// ---------------- gate: sigmoid(tanh(t*Wg1+bg1)@Wg2+bg2) -------------------
__global__ __launch_bounds__(128) void gate_kernel(
    const float* __restrict__ t, const float* __restrict__ Wg1,
    const float* __restrict__ bg1, const float* __restrict__ Wg2,
    const float* __restrict__ bg2, float* __restrict__ gate)
{
    __shared__ float u[D];
    int j = threadIdx.x;
    float tv = t[0];
    u[j] = tanhf(tv * Wg1[j] + bg1[j]);
    __syncthreads();
    float s = bg2[j];
    #pragma unroll 8
    for (int k = 0; k < D; k++) s += u[k] * Wg2[k * D + j];
    gate[j] = 1.0f / (1.0f + expf(-s));
}

// ---- edge_index convert (int64 auto-detect) + fused degree histogram ------
__global__ __launch_bounds__(256) void convert_hist_kernel(
    const int* __restrict__ w, int* __restrict__ src32,
    int* __restrict__ dst32, int* __restrict__ counts, int E)
{
    __shared__ int flag;
    if (threadIdx.x == 0) {
        int z = 0;
        for (int k = 0; k < 64; k++) z |= w[2 * k + 1];
        flag = (z == 0) ? 1 : 0;   // all odd words zero => int64 layout
    }
    __syncthreads();
    int i64 = flag;
    int total = 2 * E;
    int stride = gridDim.x * blockDim.x;
    for (int i = blockIdx.x * blockDim.x + threadIdx.x; i < total; i += stride) {
        int v = i64 ? w[2 * i] : w[i];   // little-endian low word
        if (i < E) {
            src32[i] = v;
        } else {
            dst32[i - E] = v;
            atomicAdd(&counts[v], 1);
        }
    }
}

// ------------------- multi-block exclusive scan ----------------------------
#define SCHUNK 1024
__global__ __launch_bounds__(256) void scan_partial_kernel(
    const int* __restrict__ counts, int* __restrict__ bsums, int N)
{
    int base = blockIdx.x * SCHUNK + threadIdx.x * 4;
    int s = 0;
    if (base + 3 < N) {
        int4 v = *(const int4*)(counts + base);
        s = v.x + v.y + v.z + v.w;
    } else {
        for (int k = 0; k < 4; k++) if (base + k < N) s += counts[base + k];
    }
    #pragma unroll
    for (int off = 1; off < 64; off <<= 1) s += __shfl_xor(s, off);
    __shared__ int wsum[4];
    int lane = threadIdx.x & 63, wid = threadIdx.x >> 6;
    if (lane == 0) wsum[wid] = s;
    __syncthreads();
    if (threadIdx.x == 0)
        bsums[blockIdx.x] = wsum[0] + wsum[1] + wsum[2] + wsum[3];
}

__global__ __launch_bounds__(1024) void scan_bsums_kernel(
    int* __restrict__ bsums, int* __restrict__ total_out, int B)
{
    int t = threadIdx.x;
    int v = (t < B) ? bsums[t] : 0;
    int lane = t & 63, wid = t >> 6;
    int s = v;
    #pragma unroll
    for (int off = 1; off < 64; off <<= 1) {
        int n = __shfl_up(s, off);
        if (lane >= off) s += n;
    }
    __shared__ int wsum[16], wpre[16];
    if (lane == 63) wsum[wid] = s;
    __syncthreads();
    if (t < 16) {
        int ws = wsum[t];
        #pragma unroll
        for (int off = 1; off < 16; off <<= 1) {
            int n = __shfl_up(ws, off);
            if (t >= off) ws += n;
        }
        wpre[t] = ws;
    }
    __syncthreads();
    int wex = wid ? wpre[wid - 1] : 0;
    if (t < B) bsums[t] = wex + (s - v);      // exclusive
    if (t == 0) *total_out = wpre[15];        // grand total -> offsets[N]
}

__global__ __launch_bounds__(256) void scan_final_kernel(
    const int* __restrict__ counts, const int* __restrict__ bsums,
    int* __restrict__ offsets, int* __restrict__ cursor,
    float* __restrict__ dinv, int N)
{
    int base = blockIdx.x * SCHUNK + threadIdx.x * 4;
    int4 v = make_int4(0, 0, 0, 0);
    bool full = (base + 3 < N);
    if (full) v = *(const int4*)(counts + base);
    else {
        if (base + 0 < N) v.x = counts[base + 0];
        if (base + 1 < N) v.y = counts[base + 1];
        if (base + 2 < N) v.z = counts[base + 2];
        if (base + 3 < N) v.w = counts[base + 3];
    }
    int sum = v.x + v.y + v.z + v.w;
    int lane = threadIdx.x & 63, wid = threadIdx.x >> 6;
    int s = sum;
    #pragma unroll
    for (int off = 1; off < 64; off <<= 1) {
        int n = __shfl_up(s, off);
        if (lane >= off) s += n;
    }
    __shared__ int wsum[4], wpre[4];
    if (lane == 63) wsum[wid] = s;
    __syncthreads();
    if (threadIdx.x == 0) {
        int a = 0;
        #pragma unroll
        for (int k = 0; k < 4; k++) { wpre[k] = a; a += wsum[k]; }
    }
    __syncthreads();
    int e0 = bsums[blockIdx.x] + wpre[wid] + (s - sum);
    int4 o = make_int4(e0, e0 + v.x, e0 + v.x + v.y, e0 + v.x + v.y + v.z);
    float4 dv = make_float4(rsqrtf((float)v.x + 1.f), rsqrtf((float)v.y + 1.f),
                            rsqrtf((float)v.z + 1.f), rsqrtf((float)v.w + 1.f));
    if (full) {
        *(int4*)(offsets + base) = o;
        *(int4*)(cursor + base) = o;
        *(float4*)(dinv + base) = dv;
    } else {
        int oo[4] = { o.x, o.y, o.z, o.w };
        float dd[4] = { dv.x, dv.y, dv.z, dv.w };
        for (int k = 0; k < 4; k++)
            if (base + k < N) {
                offsets[base + k] = oo[k];
                cursor[base + k] = oo[k];
                dinv[base + k] = dd[k];
            }
    }
}

// -------------------- bucket edges by dst (CSR) ----------------------------
__global__ __launch_bounds__(256) void bucket_kernel(
    const int* __restrict__ src32, const int* __restrict__ dst32,
    const float* __restrict__ dinv, int* __restrict__ cursor,
    int2* __restrict__ edges, int E)
{
    int stride = gridDim.x * blockDim.x;
    for (int e = blockIdx.x * blockDim.x + threadIdx.x; e < E; e += stride) {
        int s = src32[e];
        int d = dst32[e];
        int pos = atomicAdd(&cursor[d], 1);
        edges[pos] = make_int2(s, __float_as_int(dinv[s] * dinv[d]));
    }
}

// ---------------- W pre-swizzle to MFMA B-fragment order -------------------
__global__ __launch_bounds__(256) void wswizzle_kernel(
    const float* __restrict__ W0, const float* __restrict__ W1,
    const float* __restrict__ W2, short8* __restrict__ Wf_hi,
    short8* __restrict__ Wf_lo)
{
    int f = blockIdx.x * 256 + threadIdx.x;   // 0..6143
    if (f >= 3 * 2048) return;
    int layer = f >> 11;
    int fi = f & 2047;
    int lane = fi & 63;
    int t = fi >> 6;                 // kc*8 + n
    int kc = t >> 3, n = t & 7;
    const float* W = (layer == 0) ? W0 : (layer == 1) ? W1 : W2;
    int krow = kc * 32 + (lane >> 4) * 8;
    int col = n * 16 + (lane & 15);
    short8 hv, lv;
    #pragma unroll
    for (int j = 0; j < 8; j++) {
        float x = W[(size_t)(krow + j) * D + col];
        unsigned hb = bf16_rne(x);
        float hf = __uint_as_float(hb << 16);
        unsigned lb = bf16_rne(x - hf);
        hv[j] = (short)hb;
        lv[j] = (short)lb;
    }
    Wf_hi[f] = hv;
    Wf_lo[f] = lv;
}

// ----------------- split-bf16 MFMA GEMM: H = X @ W -------------------------
// Block: 128 rows, 4 waves; wave w owns rows [w*32, w*32+32) and stages them
// into its PRIVATE LDS region (double-buffered per kc) with global_load_lds.
// LDS slot swizzle: slot(m, g) = m*8 + (g ^ (m&7))  (16B slots) so fragment
// ds_read_b128s are ~2-way conflicted instead of 16-way.
#define GBM 128
__device__ __forceinline__ void cvt8(const float* f, short8& hi, short8& lo) {
    #pragma unroll
    for (int j = 0; j < 8; j++) {
        unsigned hb = bf16_rne(f[j]);
        float hf = __uint_as_float(hb << 16);
        unsigned lb = bf16_rne(f[j] - hf);
        hi[j] = (short)hb;
        lo[j] = (short)lb;
    }
}

__global__ __launch_bounds__(256) void gemm_mfma_kernel(
    const float* __restrict__ X, const short8* __restrict__ Wf_hi,
    const short8* __restrict__ Wf_lo, float* __restrict__ H, int M)
{
    __shared__ float Xs[8192];   // 4 waves x 2 bufs x 1024 floats (32KB)
    int tid = threadIdx.x;
    int w = tid >> 6, lane = tid & 63;
    int m16 = lane & 15, qd = lane >> 4;
    int rowbase = blockIdx.x * GBM + w * 32;

    floatx4 acc[2][8];
    #pragma unroll
    for (int rt = 0; rt < 2; rt++)
        #pragma unroll
        for (int n = 0; n < 8; n++)
            acc[rt][n] = (floatx4)(0.f);

    #pragma unroll 1
    for (int kc = 0; kc < 4; kc++) {
        float* buf = Xs + w * 2048 + (kc & 1) * 1024;
        // stage 32 rows x 32 cols via 4 x global_load_lds (16B/lane)
        #pragma unroll
        for (int i = 0; i < 4; i++) {
            int s = i * 64 + lane;          // slot 0..255
            int m = s >> 3;
            int g = (s & 7) ^ (m & 7);      // XOR swizzle
            int row = rowbase + m;
            if (row >= M) row = M - 1;      // clamp (tail rows discarded)
            gload_lds16(X + (size_t)row * D + kc * 32 + g * 4, buf + i * 256);
        }
        __syncthreads();   // drains vmcnt: LDS-DMA complete

        float a0[8], a1[8];
        int s00 = m16 * 8 + ((2 * qd) ^ (m16 & 7));
        int s01 = m16 * 8 + ((2 * qd + 1) ^ (m16 & 7));
        int m1 = m16 + 16;
        int s10 = m1 * 8 + ((2 * qd) ^ (m1 & 7));
        int s11 = m1 * 8 + ((2 * qd + 1) ^ (m1 & 7));
        *(float4*)(a0)     = *(const float4*)(buf + s00 * 4);
        *(float4*)(a0 + 4) = *(const float4*)(buf + s01 * 4);
        *(float4*)(a1)     = *(const float4*)(buf + s10 * 4);
        *(float4*)(a1 + 4) = *(const float4*)(buf + s11 * 4);

        short8 ah[2], al[2];
        cvt8(a0, ah[0], al[0]);
        cvt8(a1, ah[1], al[1]);

        #pragma unroll
        for (int n = 0; n < 8; n++) {
            short8 bh = Wf_hi[(size_t)(kc * 8 + n) * 64 + lane];
            short8 bl = Wf_lo[(size_t)(kc * 8 + n) * 64 + lane];
            #pragma unroll
            for (int rt = 0; rt < 2; rt++) {
                acc[rt][n] = __builtin_amdgcn_mfma_f32_16x16x32_bf16(
                    ah[rt], bh, acc[rt][n], 0, 0, 0);
                acc[rt][n] = __builtin_amdgcn_mfma_f32_16x16x32_bf16(
                    ah[rt], bl, acc[rt][n], 0, 0, 0);
                acc[rt][n] = __builtin_amdgcn_mfma_f32_16x16x32_bf16(
                    al[rt], bh, acc[rt][n], 0, 0, 0);
            }
        }
    }

    // C/D layout: col = n*16 + (lane&15), row = rt*16 + (lane>>4)*4 + reg
    #pragma unroll
    for (int rt = 0; rt < 2; rt++) {
        #pragma unroll
        for (int reg = 0; reg < 4; reg++) {
            int row = rowbase + rt * 16 + qd * 4 + reg;
            if (row < M) {
                float* hp = H + (size_t)row * D + m16;
                #pragma unroll
                for (int n = 0; n < 8; n++)
                    hp[n * 16] = acc[rt][n][reg];
            }
        }
    }
}

// ------------- per-node aggregation (2 nodes/wave, 4-deep MLP) -------------
// half-wave = 32 lanes x float4 = 128 features; edge loop unrolled x4 so up
// to 8 gathers are in flight per wave (vs 1 before).
__global__ __launch_bounds__(256) void agg_kernel(
    const float* __restrict__ H, const int2* __restrict__ edges,
    const int* __restrict__ offsets, const float* __restrict__ dinv,
    const float* __restrict__ bias, const float* __restrict__ gate,
    float* __restrict__ out, int M)
{
    int t = threadIdx.x;
    int hw = t >> 5;                  // half-wave 0..7
    int l32 = t & 31;
    int node = blockIdx.x * 8 + hw;
    if (node >= M) return;

    int beg = offsets[node];
    int end = offsets[node + 1];
    const float* __restrict__ Hc = H + (size_t)l32 * 4;
    float4 acc = make_float4(0.f, 0.f, 0.f, 0.f);

    int j = beg;
    for (; j + 4 <= end; j += 4) {
        int2 e0 = edges[j + 0];
        int2 e1 = edges[j + 1];
        int2 e2 = edges[j + 2];
        int2 e3 = edges[j + 3];
        float4 h0 = *(const float4*)(Hc + (size_t)e0.x * D);
        float4 h1 = *(const float4*)(Hc + (size_t)e1.x * D);
        float4 h2 = *(const float4*)(Hc + (size_t)e2.x * D);
        float4 h3 = *(const float4*)(Hc + (size_t)e3.x * D);
        float n0 = __int_as_float(e0.y), n1 = __int_as_float(e1.y);
        float n2 = __int_as_float(e2.y), n3 = __int_as_float(e3.y);
        acc.x = fmaf(h3.x, n3, fmaf(h2.x, n2, fmaf(h1.x, n1, fmaf(h0.x, n0, acc.x))));
        acc.y = fmaf(h3.y, n3, fmaf(h2.y, n2, fmaf(h1.y, n1, fmaf(h0.y, n0, acc.y))));
        acc.z = fmaf(h3.z, n3, fmaf(h2.z, n2, fmaf(h1.z, n1, fmaf(h0.z, n0, acc.z))));
        acc.w = fmaf(h3.w, n3, fmaf(h2.w, n2, fmaf(h1.w, n1, fmaf(h0.w, n0, acc.w))));
    }
    for (; j < end; j++) {
        int2 e = edges[j];
        float nv = __int_as_float(e.y);
        float4 hv = *(const float4*)(Hc + (size_t)e.x * D);
        acc.x = fmaf(hv.x, nv, acc.x);
        acc.y = fmaf(hv.y, nv, acc.y);
        acc.z = fmaf(hv.z, nv, acc.z);
        acc.w = fmaf(hv.w, nv, acc.w);
    }

    float di = dinv[node];
    float sn = di * di;                          // 1/deg
    float4 hs = *(const float4*)(Hc + (size_t)node * D);
    float4 bv = *(const float4*)(bias + l32 * 4);
    float4 gv = *(const float4*)(gate + l32 * 4);
    acc.x = fmaxf(fmaf(hs.x, sn, acc.x) + bv.x, 0.f) * gv.x;
    acc.y = fmaxf(fmaf(hs.y, sn, acc.y) + bv.y, 0.f) * gv.y;
    acc.z = fmaxf(fmaf(hs.z, sn, acc.z) + bv.z, 0.f) * gv.z;
    acc.w = fmaxf(fmaf(hs.w, sn, acc.w) + bv.w, 0.f) * gv.w;
    *(float4*)(out + (size_t)node * D + l32 * 4) = acc;
}

// ---------------------------------------------------------------------------
static inline size_t align_up(size_t v, size_t a) { return (v + a - 1) & ~(a - 1); }

extern "C" void kernel_launch(void* const* d_in, const int* in_sizes, int n_in,
                              void* d_out, int out_size, void* d_ws, size_t ws_size,
                              hipStream_t stream)
{
    const float* x   = (const float*)d_in[0];
    const int*   ei  = (const int*)d_in[1];   // int32 or int64 (auto-detected)
    const float* ts  = (const float*)d_in[2];
    const float* Wl[3] = { (const float*)d_in[3], (const float*)d_in[5], (const float*)d_in[7] };
    const float* bl[3] = { (const float*)d_in[4], (const float*)d_in[6], (const float*)d_in[8] };
    const float* Wg1 = (const float*)d_in[9];
    const float* bg1 = (const float*)d_in[10];
    const float* Wg2 = (const float*)d_in[11];
    const float* bg2 = (const float*)d_in[12];

    const int N = in_sizes[0] / D;      // 100000
    const int E = in_sizes[1] / 2;      // 600000
    const int NB = (N + SCHUNK - 1) / SCHUNK;   // scan blocks

    // workspace carve (all 256B aligned)
    char* p = (char*)d_ws;
    float* h    = (float*)p; p += align_up((size_t)N * D * 4, 256);
    float* buf0 = (float*)p; p += align_up((size_t)N * D * 4, 256);
    int* src32  = (int*)p;   p += align_up((size_t)E * 4, 256);
    int* dst32  = (int*)p;   p += align_up((size_t)E * 4, 256);
    int* counts = (int*)p;   p += align_up((size_t)N * 4, 256);
    float* dinv = (float*)p; p += align_up((size_t)N * 4, 256);
    int* offs   = (int*)p;   p += align_up((size_t)(N + 1) * 4, 256);
    int* cursor = (int*)p;   p += align_up((size_t)N * 4, 256);
    int2* edges = (int2*)p;  p += align_up((size_t)E * 8, 256);
    float* gate = (float*)p; p += align_up((size_t)D * 4, 256);
    int* bsums  = (int*)p;   p += align_up((size_t)NB * 4, 256);
    short8* Wf_hi = (short8*)p; p += align_up((size_t)3 * 2048 * 16, 256);
    short8* Wf_lo = (short8*)p; p += align_up((size_t)3 * 2048 * 16, 256);
    (void)ws_size; (void)n_in; (void)out_size;

    hipMemsetAsync(counts, 0, (size_t)N * 4, stream);
    gate_kernel<<<1, 128, 0, stream>>>(ts, Wg1, bg1, Wg2, bg2, gate);
    wswizzle_kernel<<<24, 256, 0, stream>>>(Wl[0], Wl[1], Wl[2], Wf_hi, Wf_lo);
    convert_hist_kernel<<<1024, 256, 0, stream>>>(ei, src32, dst32, counts, E);
    scan_partial_kernel<<<NB, 256, 0, stream>>>(counts, bsums, N);
    scan_bsums_kernel<<<1, 1024, 0, stream>>>(bsums, offs + N, NB);
    scan_final_kernel<<<NB, 256, 0, stream>>>(counts, bsums, offs, cursor, dinv, N);
    bucket_kernel<<<1024, 256, 0, stream>>>(src32, dst32, dinv, cursor, edges, E);

    const float* xin = x;
    float* outs[3] = { buf0, buf0, (float*)d_out };
    for (int l = 0; l < 3; l++) {
        gemm_mfma_kernel<<<(N + GBM - 1) / GBM, 256, 0, stream>>>(
            xin, Wf_hi + (size_t)l * 2048, Wf_lo + (size_t)l * 2048, h, N);
        agg_kernel<<<(N + 7) / 8, 256, 0, stream>>>(h, edges, offs, dinv,
                                                    bl[l], gate, outs[l], N);
        xin = outs[l];
    }
}